// Round 8
// baseline (49.117 us; speedup 1.0000x reference)
//
#include <hip/hip_runtime.h>

// NeRF volume compositing, MI355X.
// 2 rays per 64-lane wave (32 lanes/ray), 4 contiguous samples per lane.
// T before a sample is the plain exclusive prefix product of (1-a):
// factors in (0,1], T monotone non-increasing, so "dead stays dead"
// truncation == thresholding the prefix product.
//
// KEY STRUCTURE (round 8): the bulk loads are issued SPECULATIVELY at the
// predicted layout (start = ray*128, count = 128) in parallel with the
// rays_a metadata load -- one memory round-trip per wave instead of two.
// Safe: reads are side-effect-free and the host only enables speculation
// when ray*128+128 <= N for every ray (bounds-proof independent of data).
// A wave-uniform match check falls back to the fully general gather path.
//
// Cross-lane work is pure DPP (zero LDS-pipe ops in the hot path):
//  scan:   row_shr 1/2/4/8 (mul, old=1) + row_bcast15 rm=0xA -> segmented
//          32-lane inclusive product; exclusive via wave_shr:1 + sl==0 fix.
//  reduce: row_shr 1/2/4/8 (add, old=0) + row_bcast15 rm=0xA -> segment
//          sums land in lanes 31 and 63 (the only readers).

#define BW 4   // waves per block

typedef float f4a __attribute__((ext_vector_type(4), aligned(4)));

template<int CTRL, int RM, unsigned OLD>
__device__ __forceinline__ float dpp_f(float v) {
    return __int_as_float(__builtin_amdgcn_update_dpp(
        (int)OLD, __float_as_int(v), CTRL, RM, 0xF, false));
}

__device__ __forceinline__ float seg_sum32_hi(float v) {
    v += dpp_f<0x111, 0xF, 0u>(v);   // += lane-1 (row_shr:1)
    v += dpp_f<0x112, 0xF, 0u>(v);
    v += dpp_f<0x114, 0xF, 0u>(v);
    v += dpp_f<0x118, 0xF, 0u>(v);   // lanes 15/31/47/63 hold row sums
    v += dpp_f<0x142, 0xA, 0u>(v);   // rows 1,3 += prev row's lane15 sum
    return v;                        // lanes 31/63 = full segment sums
}

struct Ld { float4 sg, dt, tt, c0, c1, c2; };

__global__ __launch_bounds__(256) void vr_main(
    const float* __restrict__ sigmas, const float* __restrict__ rgbs,
    const float* __restrict__ deltas, const float* __restrict__ ts,
    const int* __restrict__ rays_a, const float* __restrict__ thr_p,
    float* __restrict__ out, float* __restrict__ blk_ws,
    int R, int use_ws, int spec_ok)
{
    __shared__ float bsum[BW];

    const int wib  = (int)(threadIdx.x >> 6);
    const int wid  = (int)blockIdx.x * BW + wib;
    const int lane = (int)(threadIdx.x & 63);
    const int half = lane >> 5;
    const int sl   = lane & 31;
    const int ray  = 2 * wid + half;
    const bool inR = ray < R;
    const float thr = thr_p[0];

    // ---- Speculative bulk loads at predicted layout (no meta dependency).
    const int p_start = ray << 7;          // predicted start (128/ray, packed)
    Ld d;
    if (spec_ok && inR) {
        d.sg = *(const float4*)(sigmas + p_start + 4 * sl);
        d.dt = *(const float4*)(deltas + p_start + 4 * sl);
        d.tt = *(const float4*)(ts     + p_start + 4 * sl);
        const float* rg = rgbs + 3 * ((size_t)p_start + 4 * sl); // 48B-aligned
        d.c0 = *(const float4*)(rg + 0);
        d.c1 = *(const float4*)(rg + 4);
        d.c2 = *(const float4*)(rg + 8);
    }

    // ---- Metadata (flies concurrently with the speculative loads).
    int ridx = 0, start = 0, count = 0;
    if (inR) {
        ridx  = rays_a[3 * ray + 0];
        start = rays_a[3 * ray + 1];
        count = rays_a[3 * ray + 2];
    }
    const bool match = spec_ok && inR && (start == p_start) && (count == 128);
    const bool fastw = __all(match);

    if (!fastw) {
        // General path: per-sample gather from actual metadata (overwrites
        // any speculative registers consistently across the wave).
        float sg[4], dt[4], tt[4], rr[4], gg[4], bb[4];
        #pragma unroll
        for (int i = 0; i < 4; ++i) {
            const int s = 4 * sl + i;
            const bool vi = inR && (s < count);
            sg[i] = dt[i] = tt[i] = rr[i] = gg[i] = bb[i] = 0.f;
            if (vi) {
                sg[i] = sigmas[start + s];
                dt[i] = deltas[start + s];
                tt[i] = ts[start + s];
                const float* rg = rgbs + 3 * ((size_t)start + s);
                rr[i] = rg[0]; gg[i] = rg[1]; bb[i] = rg[2];
            }
        }
        d.sg = make_float4(sg[0], sg[1], sg[2], sg[3]);
        d.dt = make_float4(dt[0], dt[1], dt[2], dt[3]);
        d.tt = make_float4(tt[0], tt[1], tt[2], tt[3]);
        d.c0 = make_float4(rr[0], gg[0], bb[0], rr[1]);
        d.c1 = make_float4(gg[1], bb[1], rr[2], gg[2]);
        d.c2 = make_float4(bb[2], rr[3], gg[3], bb[3]);
    }

    // Invalid lanes: sg=dt=0 -> fe=1 (scan identity); w gated by v[i].
    float fe[4] = { __expf(-d.sg.x * d.dt.x), __expf(-d.sg.y * d.dt.y),
                    __expf(-d.sg.z * d.dt.z), __expf(-d.sg.w * d.dt.w) };
    bool v[4];
    #pragma unroll
    for (int i = 0; i < 4; ++i) v[i] = inR && (4 * sl + i) < count;

    // Segmented 32-lane inclusive prefix product (5 DPP muls, old=1).
    const float fprod = (fe[0] * fe[1]) * (fe[2] * fe[3]);
    float inc = fprod;
    inc *= dpp_f<0x111, 0xF, 0x3f800000u>(inc);   // row_shr:1
    inc *= dpp_f<0x112, 0xF, 0x3f800000u>(inc);
    inc *= dpp_f<0x114, 0xF, 0x3f800000u>(inc);
    inc *= dpp_f<0x118, 0xF, 0x3f800000u>(inc);
    inc *= dpp_f<0x142, 0xA, 0x3f800000u>(inc);   // row_bcast15 -> rows 1,3

    // Exclusive prefix: wave_shr:1; segment heads (sl==0) -> 1.
    float ex = dpp_f<0x138, 0xF, 0x3f800000u>(inc);
    float T = (sl == 0) ? 1.f : ex;

    float w[4];
    float cnt = 0.f;
    #pragma unroll
    for (int i = 0; i < 4; ++i) {
        const bool alive = v[i] && (T > thr);
        const float Tn = T * fe[i];
        w[i] = alive ? (T - Tn) : 0.f;
        cnt += alive ? 1.f : 0.f;
        T = Tn;
    }

    // Per-sample weights (ws base is odd floats -> 4B-aligned wide store).
    float* wsp = out + 1 + 5 * (size_t)R + (size_t)start + 4 * sl;
    if (fastw) {
        f4a wv; wv.x = w[0]; wv.y = w[1]; wv.z = w[2]; wv.w = w[3];
        *(f4a*)wsp = wv;
    } else {
        #pragma unroll
        for (int i = 0; i < 4; ++i) if (v[i]) wsp[i] = w[i];
    }

    // Per-ray reductions (segment sums land in lanes 31 and 63).
    float op  = (w[0] + w[1]) + (w[2] + w[3]);
    float dep = fmaf(w[0], d.tt.x, fmaf(w[1], d.tt.y, fmaf(w[2], d.tt.z, w[3] * d.tt.w)));
    float cr  = fmaf(w[0], d.c0.x, fmaf(w[1], d.c0.w, fmaf(w[2], d.c1.z, w[3] * d.c2.y)));
    float cg  = fmaf(w[0], d.c0.y, fmaf(w[1], d.c1.x, fmaf(w[2], d.c1.w, w[3] * d.c2.z)));
    float cb  = fmaf(w[0], d.c0.z, fmaf(w[1], d.c1.y, fmaf(w[2], d.c2.x, w[3] * d.c2.w)));

    op  = seg_sum32_hi(op);
    dep = seg_sum32_hi(dep);
    cr  = seg_sum32_hi(cr);
    cg  = seg_sum32_hi(cg);
    cb  = seg_sum32_hi(cb);
    cnt = seg_sum32_hi(cnt);

    if (sl == 31 && inR) {
        out[1 + ridx]                 = op;
        out[1 + R + ridx]             = dep;
        out[1 + 2 * R + 3 * ridx + 0] = cr;
        out[1 + 2 * R + 3 * ridx + 1] = cg;
        out[1 + 2 * R + 3 * ridx + 2] = cb;
    }

    // total_samples: block-level partial (exact: integer-valued floats).
    const float cw =
        __int_as_float(__builtin_amdgcn_readlane(__float_as_int(cnt), 31)) +
        __int_as_float(__builtin_amdgcn_readlane(__float_as_int(cnt), 63));
    if (lane == 0) bsum[wib] = cw;
    __syncthreads();
    if (threadIdx.x == 0) {
        const float t = (bsum[0] + bsum[1]) + (bsum[2] + bsum[3]);
        if (use_ws) blk_ws[blockIdx.x] = t;
        else        atomicAdd(&out[0], t);   // rare fallback (tiny ws)
    }
}

// Single small block: sum per-block partials (nb floats) -> out[0].
// Fixed summation order per replay; values are integers < 2^24 -> exact.
__global__ __launch_bounds__(256) void vr_total(
    const float* __restrict__ blk_ws, float* __restrict__ out, int nb)
{
    __shared__ float sm[4];
    float s = 0.f;
    for (int i = (int)threadIdx.x; i < nb; i += 256) s += blk_ws[i];
    #pragma unroll
    for (int d = 32; d; d >>= 1) s += __shfl_xor(s, d, 64);
    if ((threadIdx.x & 63) == 0) sm[threadIdx.x >> 6] = s;
    __syncthreads();
    if (threadIdx.x == 0) out[0] = (sm[0] + sm[1]) + (sm[2] + sm[3]);
}

extern "C" void kernel_launch(void* const* d_in, const int* in_sizes, int n_in,
                              void* d_out, int out_size, void* d_ws, size_t ws_size,
                              hipStream_t stream) {
    const float* sigmas = (const float*)d_in[0];
    const float* rgbs   = (const float*)d_in[1];
    const float* deltas = (const float*)d_in[2];
    const float* ts     = (const float*)d_in[3];
    const int*   rays_a = (const int*)d_in[4];
    const float* thr    = (const float*)d_in[5];
    const int R = in_sizes[4] / 3;
    float* out = (float*)d_out;
    float* blk_ws = (float*)d_ws;

    const int grid = (R + 2 * BW - 1) / (2 * BW);   // 2 rays/wave, BW waves/blk
    const int use_ws = (ws_size >= (size_t)grid * sizeof(float)) ? 1 : 0;

    // Speculation legality: predicted reads ray*128..ray*128+127 must be
    // in-bounds for every ray regardless of rays_a contents.
    const long long need = (long long)R * 128;
    const int spec_ok = (in_sizes[0] >= need) && (in_sizes[2] >= need) &&
                        (in_sizes[3] >= need) &&
                        ((long long)in_sizes[1] >= 3 * need);

    if (!use_ws)  // atomic fallback needs a zero seed for out[0]
        hipMemsetAsync(d_out, 0, 4, stream);

    vr_main<<<grid, 256, 0, stream>>>(sigmas, rgbs, deltas, ts, rays_a, thr,
                                      out, blk_ws, R, use_ws, spec_ok);
    if (use_ws)
        vr_total<<<1, 256, 0, stream>>>(blk_ws, out, grid);
}

// Round 9
// 49.013 us; speedup vs baseline: 1.0021x; 1.0021x over previous
//
#include <hip/hip_runtime.h>

// NeRF volume compositing, MI355X.
// 2 rays per 64-lane wave (32 lanes/ray), 4 contiguous samples per lane.
// T before a sample is the plain exclusive prefix product of (1-a):
// factors in (0,1], T monotone non-increasing, so "dead stays dead"
// truncation == thresholding the prefix product.
//
// Bandwidth accounting (round-9 insight): app-level traffic is 236.8 MB
// (202 read + 35 write) regardless of L3 hits; at the 6.29 TB/s measured
// copy ceiling that's a ~38 us floor for vr_main. We run ~42 us => ~89%
// of the achievable app-level bandwidth. Remaining levers are write-slot
// efficiency (aligned ws stores below) and reduce/launch overhead.
//
// Cross-lane work is pure DPP (zero LDS-pipe ops in the hot path):
//  scan:   row_shr 1/2/4/8 (mul, old=1) + row_bcast15 rm=0xA -> segmented
//          32-lane inclusive product; exclusive via wave_shr:1 + sl==0 fix.
//  reduce: row_shr 1/2/4/8 (add, old=0) + row_bcast15 rm=0xA -> segment
//          sums land in lanes 31 and 63 (the only readers).
//  ws store: wave_shl:1 redistribution -> all stores 16B-aligned, zero
//          cache-line-crossing transactions (span is offset by 4B).

#define BW 4   // waves per block

template<int CTRL, int RM, unsigned OLD>
__device__ __forceinline__ float dpp_f(float v) {
    return __int_as_float(__builtin_amdgcn_update_dpp(
        (int)OLD, __float_as_int(v), CTRL, RM, 0xF, false));
}

__device__ __forceinline__ float seg_sum32_hi(float v) {
    v += dpp_f<0x111, 0xF, 0u>(v);   // += lane-1 (row_shr:1)
    v += dpp_f<0x112, 0xF, 0u>(v);
    v += dpp_f<0x114, 0xF, 0u>(v);
    v += dpp_f<0x118, 0xF, 0u>(v);   // lanes 15/31/47/63 hold row sums
    v += dpp_f<0x142, 0xA, 0u>(v);   // rows 1,3 += prev row's lane15 sum
    return v;                        // lanes 31/63 = full segment sums
}

__global__ __launch_bounds__(256) void vr_main(
    const float* __restrict__ sigmas, const float* __restrict__ rgbs,
    const float* __restrict__ deltas, const float* __restrict__ ts,
    const int* __restrict__ rays_a, const float* __restrict__ thr_p,
    float* __restrict__ out, float* __restrict__ blk_ws,
    int R, int use_ws)
{
    __shared__ float bsum[BW];

    const int wib  = (int)(threadIdx.x >> 6);
    const int wid  = (int)blockIdx.x * BW + wib;
    const int lane = (int)(threadIdx.x & 63);
    const int half = lane >> 5;
    const int sl   = lane & 31;
    const int ray  = 2 * wid + half;
    const bool inR = ray < R;
    const float thr = thr_p[0];

    int ridx = 0, start = 0, count = 0;
    if (inR) {
        ridx  = rays_a[3 * ray + 0];
        start = rays_a[3 * ray + 1];
        count = rays_a[3 * ray + 2];
    }

    // Fast path requires globally-packed layout (start == ray*128) so the
    // wave's two rays form one contiguous 256-float ws span.
    const bool packed = inR && (start == (ray << 7)) && (count == 128);
    const bool fastw  = __all(packed);

    float4 sg4, dt4, tt4, c0, c1, c2;
    if (fastw) {
        // Six independent 16B loads, issued back-to-back (max MLP).
        sg4 = *(const float4*)(sigmas + start + 4 * sl);
        dt4 = *(const float4*)(deltas + start + 4 * sl);
        tt4 = *(const float4*)(ts     + start + 4 * sl);
        const float* rg = rgbs + 3 * ((size_t)start + 4 * sl);  // 48B-aligned
        c0 = *(const float4*)(rg + 0);
        c1 = *(const float4*)(rg + 4);
        c2 = *(const float4*)(rg + 8);
    } else {
        float sg[4], dt[4], tt[4], rr[4], gg[4], bb[4];
        #pragma unroll
        for (int i = 0; i < 4; ++i) {
            const int s = 4 * sl + i;
            const bool vi = inR && (s < count);
            sg[i] = dt[i] = tt[i] = rr[i] = gg[i] = bb[i] = 0.f;
            if (vi) {
                sg[i] = sigmas[start + s];
                dt[i] = deltas[start + s];
                tt[i] = ts[start + s];
                const float* rg = rgbs + 3 * ((size_t)start + s);
                rr[i] = rg[0]; gg[i] = rg[1]; bb[i] = rg[2];
            }
        }
        sg4 = make_float4(sg[0], sg[1], sg[2], sg[3]);
        dt4 = make_float4(dt[0], dt[1], dt[2], dt[3]);
        tt4 = make_float4(tt[0], tt[1], tt[2], tt[3]);
        c0  = make_float4(rr[0], gg[0], bb[0], rr[1]);
        c1  = make_float4(gg[1], bb[1], rr[2], gg[2]);
        c2  = make_float4(bb[2], rr[3], gg[3], bb[3]);
    }

    // Invalid lanes: sg=dt=0 -> fe=1 (scan identity); w gated by v[i].
    float fe[4] = { __expf(-sg4.x * dt4.x), __expf(-sg4.y * dt4.y),
                    __expf(-sg4.z * dt4.z), __expf(-sg4.w * dt4.w) };
    bool v[4];
    #pragma unroll
    for (int i = 0; i < 4; ++i) v[i] = inR && (4 * sl + i) < count;

    // Segmented 32-lane inclusive prefix product (5 DPP muls, old=1).
    const float fprod = (fe[0] * fe[1]) * (fe[2] * fe[3]);
    float inc = fprod;
    inc *= dpp_f<0x111, 0xF, 0x3f800000u>(inc);   // row_shr:1
    inc *= dpp_f<0x112, 0xF, 0x3f800000u>(inc);
    inc *= dpp_f<0x114, 0xF, 0x3f800000u>(inc);
    inc *= dpp_f<0x118, 0xF, 0x3f800000u>(inc);
    inc *= dpp_f<0x142, 0xA, 0x3f800000u>(inc);   // row_bcast15 -> rows 1,3

    // Exclusive prefix: wave_shr:1; segment heads (sl==0) -> 1.
    float ex = dpp_f<0x138, 0xF, 0x3f800000u>(inc);
    float T = (sl == 0) ? 1.f : ex;

    float w[4];
    float cnt = 0.f;
    #pragma unroll
    for (int i = 0; i < 4; ++i) {
        const bool alive = v[i] && (T > thr);
        const float Tn = T * fe[i];
        w[i] = alive ? (T - Tn) : 0.f;
        cnt += alive ? 1.f : 0.f;
        T = Tn;
    }

    // ---- Per-sample weights.
    const size_t wsbase = 1 + 5 * (size_t)R;   // odd float index
    if (fastw) {
        // Wave span = floats [WB, WB+256), WB odd. Redistribute one float
        // down-lane so every wide store is 16B-aligned (no line crossing):
        // lane l stores span-relative [4l+3, 4l+7) = {w3_self, w012_next}.
        const size_t WB = wsbase + ((size_t)wid << 8);
        const float n0 = dpp_f<0x130, 0xF, 0u>(w[0]);   // wave_shl:1 (l <- l+1)
        const float n1 = dpp_f<0x130, 0xF, 0u>(w[1]);
        const float n2 = dpp_f<0x130, 0xF, 0u>(w[2]);
        if (lane < 63) {
            *(float4*)(out + WB + 3 + 4 * lane) = make_float4(w[3], n0, n1, n2);
        } else {
            out[WB + 255] = w[3];                       // span tail
        }
        if (lane == 0) {                                // span head (3 floats)
            out[WB + 0] = w[0];
            out[WB + 1] = w[1];
            out[WB + 2] = w[2];
        }
    } else {
        float* wsp = out + wsbase + (size_t)start + 4 * sl;
        #pragma unroll
        for (int i = 0; i < 4; ++i) if (v[i]) wsp[i] = w[i];
    }

    // Per-ray reductions (segment sums land in lanes 31 and 63).
    float op  = (w[0] + w[1]) + (w[2] + w[3]);
    float dep = fmaf(w[0], tt4.x, fmaf(w[1], tt4.y, fmaf(w[2], tt4.z, w[3] * tt4.w)));
    float cr  = fmaf(w[0], c0.x, fmaf(w[1], c0.w, fmaf(w[2], c1.z, w[3] * c2.y)));
    float cg  = fmaf(w[0], c0.y, fmaf(w[1], c1.x, fmaf(w[2], c1.w, w[3] * c2.z)));
    float cb  = fmaf(w[0], c0.z, fmaf(w[1], c1.y, fmaf(w[2], c2.x, w[3] * c2.w)));

    op  = seg_sum32_hi(op);
    dep = seg_sum32_hi(dep);
    cr  = seg_sum32_hi(cr);
    cg  = seg_sum32_hi(cg);
    cb  = seg_sum32_hi(cb);
    cnt = seg_sum32_hi(cnt);

    if (sl == 31 && inR) {
        out[1 + ridx]                 = op;
        out[1 + R + ridx]             = dep;
        out[1 + 2 * R + 3 * ridx + 0] = cr;
        out[1 + 2 * R + 3 * ridx + 1] = cg;
        out[1 + 2 * R + 3 * ridx + 2] = cb;
    }

    // total_samples: per-block partial (integer-valued floats -> exact).
    const float cw =
        __int_as_float(__builtin_amdgcn_readlane(__float_as_int(cnt), 31)) +
        __int_as_float(__builtin_amdgcn_readlane(__float_as_int(cnt), 63));
    if (lane == 0) bsum[wib] = cw;
    __syncthreads();
    if (threadIdx.x == 0) {
        const float t = (bsum[0] + bsum[1]) + (bsum[2] + bsum[3]);
        if (use_ws) blk_ws[blockIdx.x] = t;
        else        atomicAdd(&out[0], t);   // rare fallback (tiny ws)
    }
}

// Single small block: sum per-block partials (nb floats) -> out[0].
// Fixed per-replay summation order; integer-valued floats -> exact.
__global__ __launch_bounds__(256) void vr_total(
    const float* __restrict__ blk_ws, float* __restrict__ out, int nb)
{
    __shared__ float sm[4];
    float s = 0.f;
    for (int i = (int)threadIdx.x; i < nb; i += 256) s += blk_ws[i];
    #pragma unroll
    for (int d = 32; d; d >>= 1) s += __shfl_xor(s, d, 64);
    if ((threadIdx.x & 63) == 0) sm[threadIdx.x >> 6] = s;
    __syncthreads();
    if (threadIdx.x == 0) out[0] = (sm[0] + sm[1]) + (sm[2] + sm[3]);
}

extern "C" void kernel_launch(void* const* d_in, const int* in_sizes, int n_in,
                              void* d_out, int out_size, void* d_ws, size_t ws_size,
                              hipStream_t stream) {
    const float* sigmas = (const float*)d_in[0];
    const float* rgbs   = (const float*)d_in[1];
    const float* deltas = (const float*)d_in[2];
    const float* ts     = (const float*)d_in[3];
    const int*   rays_a = (const int*)d_in[4];
    const float* thr    = (const float*)d_in[5];
    const int R = in_sizes[4] / 3;
    float* out = (float*)d_out;
    float* blk_ws = (float*)d_ws;

    const int grid = (R + 2 * BW - 1) / (2 * BW);   // 2 rays/wave, BW waves/blk
    const int use_ws = (ws_size >= (size_t)grid * sizeof(float)) ? 1 : 0;

    if (!use_ws)  // atomic fallback needs a zero seed for out[0]
        hipMemsetAsync(d_out, 0, 4, stream);

    vr_main<<<grid, 256, 0, stream>>>(sigmas, rgbs, deltas, ts, rays_a, thr,
                                      out, blk_ws, R, use_ws);
    if (use_ws)
        vr_total<<<1, 256, 0, stream>>>(blk_ws, out, grid);
}

// Round 11
// 43.741 us; speedup vs baseline: 1.1229x; 1.1205x over previous
//
#include <hip/hip_runtime.h>

// NeRF volume compositing, MI355X — consolidated best configuration
// (round-6 structure; every other variant measured neutral or worse).
//
// 2 rays per 64-lane wave (32 lanes/ray), 4 contiguous samples per lane.
// T before a sample is the plain exclusive prefix product of (1-a):
// factors in (0,1], T monotone non-increasing, so "dead stays dead"
// truncation == thresholding the prefix product.
//
// Measured-neutral-or-worse (reverted): LDS rgb transpose (r4), NT stores
// (r5), same-address per-block atomics (r5), NIT=4 software pipeline (r7),
// speculative loads (r8), aligned ws-store redistribution (r9).
//
// ROUND-10 CORRECTNESS LESSON: consuming a cross-lane reduce result only
// inside a divergent branch lets the compiler sink the ds_swizzle/DPP
// tail into the branch, where EXEC excludes the source lanes (observed:
// total_samples exactly halved). Fix: consume via readlane at FULL exec
// and pin the reduced value with an empty asm so it cannot be sunk.
//
// Cross-lane work is pure DPP except one ds_swizzle per reduced var:
//  scan:   row_shr 1/2/4/8 (mul, old=1) + row_bcast15 rm=0xA -> segmented
//          32-lane inclusive product; exclusive via own-product divide.
//  reduce: row_shl 1/2/4/8 (add, old=0) + ds_swizzle xor-16 -> segment
//          sums in lanes 0 and 32 (the only readers).

template<int CTRL, int RM>
__device__ __forceinline__ float dpp_mul1(float v) {
    // v *= dpp_move(v); inactive/out-of-row sources read old = 1.0f.
    float t = __int_as_float(__builtin_amdgcn_update_dpp(
        0x3f800000, __float_as_int(v), CTRL, RM, 0xF, false));
    return v * t;
}
template<int CTRL>
__device__ __forceinline__ float dpp_add0(float v) {
    float t = __int_as_float(__builtin_amdgcn_update_dpp(
        0, __float_as_int(v), CTRL, 0xF, 0xF, false));
    return v + t;
}
__device__ __forceinline__ float seg_reduce32(float v) {
    // Correct full 32-lane segment sum in lanes 0 and 32 (the readers).
    v = dpp_add0<0x101>(v);   // += lane+1 (row_shl:1)
    v = dpp_add0<0x102>(v);
    v = dpp_add0<0x104>(v);
    v = dpp_add0<0x108>(v);   // row leaders (0,16,32,48) hold row sums
    v += __int_as_float(__builtin_amdgcn_ds_swizzle(
            __float_as_int(v), 0x401F));   // xor-16 within 32-lane group
    return v;
}

typedef float f4a __attribute__((ext_vector_type(4), aligned(4)));

__global__ __launch_bounds__(256) void vr_main(
    const float* __restrict__ sigmas, const float* __restrict__ rgbs,
    const float* __restrict__ deltas, const float* __restrict__ ts,
    const int* __restrict__ rays_a, const float* __restrict__ thr_p,
    float* __restrict__ out, float* __restrict__ cnt_ws,
    int R, int use_ws)
{
    const int wib  = (int)(threadIdx.x >> 6);
    const int wid  = (int)blockIdx.x * 4 + wib;
    const int lane = (int)(threadIdx.x & 63);
    const int half = lane >> 5;
    const int sl   = lane & 31;
    const int ray  = 2 * wid + half;
    const bool inR = ray < R;

    int ridx = 0, start = 0, count = 0;
    if (inR) {
        ridx  = rays_a[3 * ray + 0];
        start = rays_a[3 * ray + 1];
        count = rays_a[3 * ray + 2];
    }
    const float thr = thr_p[0];

    const bool ok = inR && (count == 128) && ((start & 3) == 0);
    const bool fastw = __all(ok);

    float fe[4], tv[4], rr[4], gg[4], bb[4];
    bool  v[4];

    if (fastw) {
        // Six independent 16B loads, issued back-to-back (max MLP).
        const float4 sg4 = *(const float4*)(sigmas + start + 4 * sl);
        const float4 dt4 = *(const float4*)(deltas + start + 4 * sl);
        const float4 tt4 = *(const float4*)(ts     + start + 4 * sl);
        const float* rg = rgbs + 3 * ((size_t)start + 4 * sl);  // 48B-aligned
        const float4 c0 = *(const float4*)(rg + 0);
        const float4 c1 = *(const float4*)(rg + 4);
        const float4 c2 = *(const float4*)(rg + 8);

        fe[0] = __expf(-sg4.x * dt4.x);
        fe[1] = __expf(-sg4.y * dt4.y);
        fe[2] = __expf(-sg4.z * dt4.z);
        fe[3] = __expf(-sg4.w * dt4.w);
        tv[0] = tt4.x; tv[1] = tt4.y; tv[2] = tt4.z; tv[3] = tt4.w;
        rr[0] = c0.x; gg[0] = c0.y; bb[0] = c0.z;
        rr[1] = c0.w; gg[1] = c1.x; bb[1] = c1.y;
        rr[2] = c1.z; gg[2] = c1.w; bb[2] = c2.x;
        rr[3] = c2.y; gg[3] = c2.z; bb[3] = c2.w;
        v[0] = v[1] = v[2] = v[3] = true;
    } else {
        #pragma unroll
        for (int i = 0; i < 4; ++i) {
            const int s = 4 * sl + i;
            const bool vi = inR && (s < count);
            v[i] = vi;
            float sg = 0.f, dt = 0.f;
            tv[i] = 0.f; rr[i] = 0.f; gg[i] = 0.f; bb[i] = 0.f;
            if (vi) {
                sg = sigmas[start + s];
                dt = deltas[start + s];
                tv[i] = ts[start + s];
                const float* rg = rgbs + 3 * ((size_t)start + s);
                rr[i] = rg[0]; gg[i] = rg[1]; bb[i] = rg[2];
            }
            fe[i] = vi ? __expf(-sg * dt) : 1.f;
        }
    }

    // Per-lane product, then 32-lane segmented inclusive DPP scan.
    const float fprod = (fe[0] * fe[1]) * (fe[2] * fe[3]);
    float inc = fprod;
    inc = dpp_mul1<0x111, 0xF>(inc);   // row_shr:1
    inc = dpp_mul1<0x112, 0xF>(inc);   // row_shr:2
    inc = dpp_mul1<0x114, 0xF>(inc);   // row_shr:4
    inc = dpp_mul1<0x118, 0xF>(inc);   // row_shr:8
    inc = dpp_mul1<0x142, 0xA>(inc);   // row_bcast15 -> rows 1,3 only

    // Exclusive prefix = inclusive / own product (well-conditioned for
    // any in-range chunk; sl==0 -> exactly 1).
    float T = inc / fprod;

    float w[4];
    float cnt = 0.f;
    #pragma unroll
    for (int i = 0; i < 4; ++i) {
        const bool alive = v[i] && (T > thr);
        const float Tn = T * fe[i];
        w[i] = alive ? (T - Tn) : 0.f;
        cnt += alive ? 1.f : 0.f;
        T = Tn;
    }

    // Per-sample weights (ws region base is odd -> 4B-aligned wide store;
    // L2 write-combining handles the line-crossing).
    float* wsp = out + 1 + 5 * (size_t)R + (size_t)start + 4 * sl;
    if (fastw) {
        f4a wv; wv.x = w[0]; wv.y = w[1]; wv.z = w[2]; wv.w = w[3];
        *(f4a*)wsp = wv;
    } else {
        #pragma unroll
        for (int i = 0; i < 4; ++i) if (v[i]) wsp[i] = w[i];
    }

    // Per-ray reductions (segment sums land in lanes 0 and 32).
    float op  = (w[0] + w[1]) + (w[2] + w[3]);
    float dep = fmaf(w[0], tv[0], fmaf(w[1], tv[1], fmaf(w[2], tv[2], w[3] * tv[3])));
    float cr  = fmaf(w[0], rr[0], fmaf(w[1], rr[1], fmaf(w[2], rr[2], w[3] * rr[3])));
    float cg  = fmaf(w[0], gg[0], fmaf(w[1], gg[1], fmaf(w[2], gg[2], w[3] * gg[3])));
    float cb  = fmaf(w[0], bb[0], fmaf(w[1], bb[1], fmaf(w[2], bb[2], w[3] * bb[3])));

    op  = seg_reduce32(op);
    dep = seg_reduce32(dep);
    cr  = seg_reduce32(cr);
    cg  = seg_reduce32(cg);
    cb  = seg_reduce32(cb);
    cnt = seg_reduce32(cnt);

    // Pin the reduced value at full EXEC so the compiler cannot sink the
    // DPP/ds_swizzle chain into a divergent branch (round-10 bug).
    asm volatile("" : "+v"(cnt));

    if (sl == 0 && inR) {
        out[1 + ridx]             = op;
        out[1 + R + ridx]         = dep;
        out[1 + 2*R + 3*ridx + 0] = cr;
        out[1 + 2*R + 3*ridx + 1] = cg;
        out[1 + 2*R + 3*ridx + 2] = cb;
    }

    // total_samples: one per-wave partial (both rays). cw is computed at
    // FULL exec (readlane ignores exec; inputs already materialized).
    const float cw =
        __int_as_float(__builtin_amdgcn_readlane(__float_as_int(cnt), 0)) +
        __int_as_float(__builtin_amdgcn_readlane(__float_as_int(cnt), 32));
    if (lane == 0) {
        if (use_ws) cnt_ws[wid] = cw;
        else        atomicAdd(&out[0], cw);   // rare fallback (tiny ws)
    }
}

// Single block: full sum of per-wave partials -> plain store to out[0]
// (overwrites poison deterministically every replay; no memset needed).
__global__ __launch_bounds__(1024) void vr_total(
    const float* __restrict__ cnt_ws, float* __restrict__ out, int nw)
{
    __shared__ float sm[16];
    float s = 0.f;
    const int n4 = nw & ~3;
    for (int i = (int)threadIdx.x * 4; i < n4; i += 4096) {
        const float4 c = *(const float4*)(cnt_ws + i);
        s += (c.x + c.y) + (c.z + c.w);
    }
    if (threadIdx.x == 0)
        for (int i = n4; i < nw; ++i) s += cnt_ws[i];
    #pragma unroll
    for (int d = 32; d; d >>= 1) s += __shfl_xor(s, d, 64);
    if ((threadIdx.x & 63) == 0) sm[threadIdx.x >> 6] = s;
    __syncthreads();
    if (threadIdx.x == 0) {
        float t = 0.f;
        #pragma unroll
        for (int k = 0; k < 16; ++k) t += sm[k];
        out[0] = t;
    }
}

extern "C" void kernel_launch(void* const* d_in, const int* in_sizes, int n_in,
                              void* d_out, int out_size, void* d_ws, size_t ws_size,
                              hipStream_t stream) {
    const float* sigmas = (const float*)d_in[0];
    const float* rgbs   = (const float*)d_in[1];
    const float* deltas = (const float*)d_in[2];
    const float* ts     = (const float*)d_in[3];
    const int*   rays_a = (const int*)d_in[4];
    const float* thr    = (const float*)d_in[5];
    const int R = in_sizes[4] / 3;
    float* out = (float*)d_out;
    float* cnt_ws = (float*)d_ws;

    const int nw = (R + 1) / 2;                       // waves (2 rays each)
    const int use_ws = (ws_size >= (size_t)nw * sizeof(float)) ? 1 : 0;

    if (!use_ws)  // atomic fallback needs a zero seed for out[0]
        hipMemsetAsync(d_out, 0, 4, stream);

    const int grid = (R + 7) / 8;  // 2 rays/wave, 4 waves/block
    vr_main<<<grid, 256, 0, stream>>>(sigmas, rgbs, deltas, ts, rays_a, thr,
                                      out, cnt_ws, R, use_ws);
    if (use_ws)
        vr_total<<<1, 1024, 0, stream>>>(cnt_ws, out, nw);
}